// Round 2
// baseline (318.999 us; speedup 1.0000x reference)
//
#include <hip/hip_runtime.h>
#include <hip/hip_bf16.h>

// ---------------------------------------------------------------------------
// SeqAttnMatch, fp32 in/out, B=64, L1=L2=1024, H=128.
// proj: split-bf16 (3-MFMA) GEMM -> f16 planes xp/yp (proven r6/r7).
// attn: BARRIER-FREE flash attention. QK and PV B-fragments both stream
// directly from L2-resident global planes (YPf / pre-transposed+swizzled
// YTsw); sP round-trip is wave-private (in-order DS). No __syncthreads,
// no vmcnt(0) drains -> 16 independent waves/CU hide all serial latency.
// ---------------------------------------------------------------------------

typedef __attribute__((ext_vector_type(8))) short    s8v;  // 8 bf16 = 16B
typedef __attribute__((ext_vector_type(8))) _Float16 h8v;  // 8 f16 = 16B
typedef __attribute__((ext_vector_type(4))) float    f4v;

#define BDIM 256

__device__ __forceinline__ f4v mfma_bf16(s8v a, s8v b, f4v c) {
    return __builtin_amdgcn_mfma_f32_16x16x32_bf16(a, b, c, 0, 0, 0);
}
__device__ __forceinline__ f4v mfma_f16(h8v a, h8v b, f4v c) {
    return __builtin_amdgcn_mfma_f32_16x16x32_f16(a, b, c, 0, 0, 0);
}
// truncation split: v = bf16(hi) + bf16(lo) + O(2^-17 v). 3 VALU ops, no RNE.
__device__ __forceinline__ void tsplit(float v, short& hi, short& lo) {
    unsigned b = __builtin_bit_cast(unsigned, v);
    unsigned hb = b & 0xFFFF0000u;
    float res = v - __builtin_bit_cast(float, hb);
    hi = (short)(hb >> 16);
    lo = (short)(__builtin_bit_cast(unsigned, res) >> 16);
}

// ---------------------------------------------------------------------------
// prep: block 0 = mask normalize -> uint8 (proven r3-r7);
//       block 1 = W trunc-split into swizzle-baked bf16 hi/lo planes;
//       blocks 2..1025 = Y -> f16 transposed, XOR-chunk-swizzled, LINEARIZED
//       per (batch, j-tile): the exact byte image attn's PV fragments read.
// ---------------------------------------------------------------------------
__global__ __launch_bounds__(1024) void prep_kernel(
    const unsigned int* __restrict__ mraw, unsigned char* __restrict__ nm,
    const float* __restrict__ W, short* __restrict__ Whsw, short* __restrict__ Wlsw,
    const float* __restrict__ Y, _Float16* __restrict__ YTsw)
{
    if (blockIdx.x >= 2) {
        // one block per (batch, j-tile): 64 j-rows x 128 h  ->  16KB f16 tile
        const int tb = blockIdx.x - 2;          // 0..1023
        const int b = tb >> 4, jt = tb & 15;
        __shared__ _Float16 sT[128][64];        // [h][chunk-swizzled j]
        const int tid = threadIdx.x;            // 1024 threads = 128 h x 8 chunks
        const int h = tid & 127, c0 = tid >> 7;
        const float* yb = Y + (size_t)(b * 1024 + jt * 64 + c0 * 8) * 128 + h;
        h8v hv;
        for (int k = 0; k < 8; ++k) hv[k] = (_Float16)yb[k * 128];
        *(h8v*)&sT[h][(c0 ^ (h & 7)) << 3] = hv;   // same swizzle attn's PV reads
        __syncthreads();
        // linear dump: global byte order == swizzled tile order
        *(h8v*)(YTsw + (size_t)tb * 8192 + tid * 8) =
            *(const h8v*)(&sT[0][0] + tid * 8);
        return;
    }
    if (blockIdx.x == 1) {
        for (int idx = threadIdx.x; idx < 16384; idx += 1024) {
            int r = idx >> 7, c = idx & 127;
            short hi, lo; tsplit(W[idx], hi, lo);
            int cs = (((c >> 3) ^ (r & 15)) << 3) | (c & 7);
            Whsw[r * 128 + cs] = hi;
            Wlsw[r * 128 + cs] = lo;
        }
        return;
    }
    __shared__ unsigned int sOrAll, sOrOdd;
    if (threadIdx.x == 0) { sOrAll = 0u; sOrOdd = 0u; }
    __syncthreads();
    unsigned int oa = 0u, oo = 0u;
    for (int i = threadIdx.x; i < 16384; i += 1024) {
        unsigned int v = mraw[i];
        oa |= v;
        if (i & 1) oo |= v;
    }
    atomicOr(&sOrAll, oa);
    atomicOr(&sOrOdd, oo);
    __syncthreads();
    const unsigned int orv = sOrAll, oro = sOrOdd;
    int mode;  // 0 = 4B stride, 1 = uint8, 2 = 2B stride, 3 = int64
    if (orv <= 1u)                       mode = (orv == 1u && oro == 0u) ? 3 : 0;
    else if ((orv & 0xFEFEFEFEu) == 0u)  mode = 1;
    else if ((orv & 0x0000FFFFu) == 0u)  mode = 0;
    else                                 mode = 2;
    const unsigned char*  b8  = (const unsigned char*)mraw;
    const unsigned short* b16 = (const unsigned short*)mraw;
    for (int j = threadIdx.x; j < 65536; j += 1024) {
        unsigned int v;
        if (mode == 0)      v = mraw[j];
        else if (mode == 1) v = b8[j];
        else if (mode == 2) v = b16[j];
        else                v = mraw[2 * j] | mraw[2 * j + 1];
        nm[j] = v ? 1 : 0;
    }
}

// ---------------------------------------------------------------------------
// Projection (all 64 batches): block = 128 rows x 64-h half, 2048 blocks.
// Split-bf16 3-MFMA GEMM, fp32 + bias + relu, stored as ONE f16 plane.
// ---------------------------------------------------------------------------
__global__ __launch_bounds__(BDIM, 4) void proj_kernel(
    const float* __restrict__ X, const float* __restrict__ Y,
    const short* __restrict__ Whsw, const short* __restrict__ Wlsw,
    const float* __restrict__ bias,
    _Float16* __restrict__ XPf, _Float16* __restrict__ YPf)
{
    __shared__ short sW[2][64][128];   // [plane][row in h-half][k swizzled]

    const int gid = blockIdx.x;
    const float* src; _Float16* dst; int local;
    if (gid < 1024) { src = X; dst = XPf; local = gid; }
    else            { src = Y; dst = YPf; local = gid - 1024; }
    const int row0 = (local >> 1) * 128, h0 = (local & 1) * 64;
    const int t = threadIdx.x, w = t >> 6, lane = t & 63, c = lane & 15, q = lane >> 4;

    {
        const short* g0 = Whsw + h0 * 128;
        const short* g1 = Wlsw + h0 * 128;
        short* l0 = &sW[0][0][0];
        short* l1 = &sW[1][0][0];
        for (int i = 0; i < 4; ++i) {
            int off = (t + i * BDIM) * 8;    // 0..8184
            *(s8v*)(l0 + off) = *(const s8v*)(g0 + off);
            *(s8v*)(l1 + off) = *(const s8v*)(g1 + off);
        }
    }

    s8v ah[2][4], al[2][4];
    for (int set = 0; set < 2; ++set) {
        const float* xr = src + (size_t)(row0 + w * 32 + set * 16 + c) * 128;
        for (int ks = 0; ks < 4; ++ks) {
            f4v v0 = *(const f4v*)&xr[ks * 32 + q * 8];
            f4v v1 = *(const f4v*)&xr[ks * 32 + q * 8 + 4];
            for (int k = 0; k < 4; ++k) {
                short hh, ll;
                tsplit(v0[k], hh, ll); ah[set][ks][k] = hh;     al[set][ks][k] = ll;
                tsplit(v1[k], hh, ll); ah[set][ks][4 + k] = hh; al[set][ks][4 + k] = ll;
            }
        }
    }
    __syncthreads();

    f4v zero = {0.f, 0.f, 0.f, 0.f};
    f4v acc[2][4];
    for (int s_ = 0; s_ < 2; ++s_) for (int n = 0; n < 4; ++n) acc[s_][n] = zero;

    for (int ks = 0; ks < 4; ++ks) {
        s8v bh[4], bl[4];
        for (int nt = 0; nt < 4; ++nt) {
            int cs = (((ks * 4 + q) ^ c) << 3);       // baked swizzle
            bh[nt] = *(const s8v*)&sW[0][nt * 16 + c][cs];
            bl[nt] = *(const s8v*)&sW[1][nt * 16 + c][cs];
        }
        for (int set = 0; set < 2; ++set)
            for (int nt = 0; nt < 4; ++nt) {
                acc[set][nt] = mfma_bf16(ah[set][ks], bh[nt], acc[set][nt]);
                acc[set][nt] = mfma_bf16(al[set][ks], bh[nt], acc[set][nt]);
                acc[set][nt] = mfma_bf16(ah[set][ks], bl[nt], acc[set][nt]);
            }
    }

    for (int set = 0; set < 2; ++set)
        for (int nt = 0; nt < 4; ++nt) {
            float bv = bias[h0 + nt * 16 + c];
            for (int r = 0; r < 4; ++r) {
                float v = fmaxf(acc[set][nt][r] + bv, 0.0f);
                size_t o = (size_t)(row0 + w * 32 + set * 16 + q * 4 + r) * 128
                           + h0 + nt * 16 + c;
                dst[o] = (_Float16)v;
            }
        }
}

// ---------------------------------------------------------------------------
// Flash attention, barrier-free: 1024 blocks = 8 xcd x 16 itile x 8 (batch
// i-tiles share an XCD -> YPf/YTsw batch slices stay L2-resident). Each of
// the 4 waves is fully independent: QK B-frags stream from YPf (k0/k1+mask
// software-prefetched one j-tile ahead), PV B-frags stream from the
// pre-transposed/pre-swizzled YTsw plane. sP C/D->A round-trip is
// wave-private LDS (in-order DS, no sync needed).
// ---------------------------------------------------------------------------
__global__ __launch_bounds__(BDIM, 4) void attn_kernel(
    const _Float16* __restrict__ YTsw, const unsigned char* __restrict__ nmask,
    const _Float16* __restrict__ XPf, const _Float16* __restrict__ YPf,
    float* __restrict__ out)
{
    __shared__ _Float16 sP[64][72];     // C/D -> A round-trip (wave-private rows)

    const int id = blockIdx.x;
    const int xcd = id & 7, rest = id >> 3;
    const int ibase = (rest & 15) * 64;
    const int b = xcd + 8 * (rest >> 4);        // batch 0..63
    const int t = threadIdx.x, wave = t >> 6, lane = t & 63;
    const int c = lane & 15, q = lane >> 4;
    const int mrow = b * 1024;

    h8v afrag[4];
    {
        const _Float16* xr = XPf + (size_t)(mrow + ibase + wave * 16 + c) * 128;
        for (int ks = 0; ks < 4; ++ks)
            afrag[ks] = *(const h8v*)&xr[ks * 32 + q * 8];
    }

    // prefetch state for the CURRENT j-tile: B k-blocks 0,1 + mask
    h8v bpre[4][2];
    int mk[4];
    for (int nt = 0; nt < 4; ++nt) {
        const _Float16* pb = YPf + (size_t)(mrow + nt * 16 + c) * 128 + q * 8;
        bpre[nt][0] = *(const h8v*)pb;
        bpre[nt][1] = *(const h8v*)(pb + 32);
        mk[nt] = nmask[mrow + nt * 16 + c];
    }

    // per-lane constant part of the PV fragment offsets (swizzle folded)
    const _Float16* yt0 = YTsw + (size_t)b * 16 * 8192 + (size_t)c * 64;
    const int sw0 = (q ^ (c & 7)) << 3;          // k2 = 0 chunk
    const int sw1 = ((4 + q) ^ (c & 7)) << 3;    // k2 = 1 chunk

    f4v zero = {0.f, 0.f, 0.f, 0.f};
    float m_i[4], l_i[4];
    f4v o[8];
    for (int r = 0; r < 4; ++r) { m_i[r] = -INFINITY; l_i[r] = 0.f; }
    for (int h = 0; h < 8; ++h) o[h] = zero;

    for (int jt = 0; jt < 16; ++jt) {
        const int jbase = jt * 64;

        // QK: k0/k1 from prefetch regs, k2/k3 fresh (hidden behind 8 MFMAs)
        f4v s[4];
        for (int nt = 0; nt < 4; ++nt) {
            const _Float16* pb = YPf + (size_t)(mrow + jbase + nt * 16 + c) * 128 + q * 8;
            h8v b2 = *(const h8v*)(pb + 64);
            h8v b3 = *(const h8v*)(pb + 96);
            f4v acc = zero;
            acc = mfma_f16(afrag[0], bpre[nt][0], acc);
            acc = mfma_f16(afrag[1], bpre[nt][1], acc);
            acc = mfma_f16(afrag[2], b2, acc);
            acc = mfma_f16(afrag[3], b3, acc);
            if (mk[nt]) { acc[0] = -1e30f; acc[1] = -1e30f; acc[2] = -1e30f; acc[3] = -1e30f; }
            s[nt] = acc;
        }

        // refill B-frag prefetch for jt+1 now: drains under softmax + PV
        if (jt < 15) {
            const int jn = jbase + 64;
            for (int nt = 0; nt < 4; ++nt) {
                const _Float16* pb = YPf + (size_t)(mrow + jn + nt * 16 + c) * 128 + q * 8;
                bpre[nt][0] = *(const h8v*)pb;
                bpre[nt][1] = *(const h8v*)(pb + 32);
            }
        }

        // fp32 online softmax (row r spread across lane&15 of each quad)
        float alpha[4];
        for (int r = 0; r < 4; ++r) {
            float mx = fmaxf(fmaxf(s[0][r], s[1][r]), fmaxf(s[2][r], s[3][r]));
            for (int off = 1; off < 16; off <<= 1)
                mx = fmaxf(mx, __shfl_xor(mx, off, 64));
            float mnew = fmaxf(m_i[r], mx);
            alpha[r] = __expf(m_i[r] - mnew);   // expf(-inf)=0 on first tile
            m_i[r] = mnew;
        }

        // P in f16; masked -> exactly 0; l from the f16-rounded P (cancels)
        float rs[4] = {0.f, 0.f, 0.f, 0.f};
        for (int nt = 0; nt < 4; ++nt) {
            for (int r = 0; r < 4; ++r) {
                float p = mk[nt] ? 0.f : __expf(s[nt][r] - m_i[r]);
                _Float16 ph = (_Float16)p;
                rs[r] += (float)ph;
                sP[wave * 16 + q * 4 + r][nt * 16 + c] = ph;
            }
        }
        for (int r = 0; r < 4; ++r) {
            float sum = rs[r];
            for (int off = 1; off < 16; off <<= 1)
                sum += __shfl_xor(sum, off, 64);
            l_i[r] = l_i[r] * alpha[r] + sum;
        }

        // mask is done being read for this tile -> refill for jt+1
        if (jt < 15) {
            const int jn = jbase + 64;
            for (int nt = 0; nt < 4; ++nt)
                mk[nt] = nmask[mrow + jn + nt * 16 + c];
        }

        for (int h = 0; h < 8; ++h)
            for (int r = 0; r < 4; ++r)
                o[h][r] *= alpha[r];

        // PV: A from wave-private sP (in-order DS), B direct from YTsw (L2)
        const _Float16* yt = yt0 + (size_t)jt * 8192;
        for (int k2 = 0; k2 < 2; ++k2) {
            h8v a = *(const h8v*)&sP[wave * 16 + c][k2 * 32 + q * 8];
            const int sw = k2 ? sw1 : sw0;
            for (int hb = 0; hb < 8; ++hb) {
                h8v bb = *(const h8v*)&yt[hb * 1024 + sw];
                o[hb] = mfma_f16(a, bb, o[hb]);
            }
        }
    }

    for (int h = 0; h < 8; ++h) {
        for (int r = 0; r < 4; ++r) {
            float v = o[h][r] / l_i[r];
            out[(size_t)(mrow + ibase + wave * 16 + q * 4 + r) * 128 + h * 16 + c] = v;
        }
    }
}

// ---------------------------------------------------------------------------
extern "C" void kernel_launch(void* const* d_in, const int* in_sizes, int n_in,
                              void* d_out, int out_size, void* d_ws, size_t ws_size,
                              hipStream_t stream) {
    const float* x    = (const float*)d_in[0];  // [64,1024,128] fp32
    const float* y    = (const float*)d_in[1];
    const unsigned int* mraw = (const unsigned int*)d_in[2];
    const float* W    = (const float*)d_in[3];  // [128,128] fp32
    const float* bias = (const float*)d_in[4];  // [128] fp32
    float* out = (float*)d_out;                 // [64,1024,128] fp32

    // ws: nmask 64KB | Whsw 32KB | Wlsw 32KB | XPf 16MB | YPf 16MB | YTsw 16MB
    unsigned char* nmask = (unsigned char*)d_ws;
    short* Whsw = (short*)((char*)d_ws + 65536);
    short* Wlsw = Whsw + 16384;
    _Float16* XPf = (_Float16*)(Wlsw + 16384);
    _Float16* YPf = XPf + (size_t)64 * 1024 * 128;
    _Float16* YTsw = YPf + (size_t)64 * 1024 * 128;

    prep_kernel<<<1026, 1024, 0, stream>>>(mraw, nmask, W, Whsw, Wlsw, y, YTsw);
    proj_kernel<<<2048, BDIM, 0, stream>>>(x, y, Whsw, Wlsw, bias, XPf, YPf);
    attn_kernel<<<1024, BDIM, 0, stream>>>(YTsw, nmask, XPf, YPf, out);
}

// Round 3
// 289.054 us; speedup vs baseline: 1.1036x; 1.1036x over previous
//
#include <hip/hip_runtime.h>
#include <hip/hip_bf16.h>

// ---------------------------------------------------------------------------
// SeqAttnMatch, fp32 in/out, B=64, L1=L2=1024, H=128.
// proj: split-bf16 (3-MFMA) GEMM -> f16 planes xp/yp, per-set compute to
//       stay under the 128-VGPR cap (spill fix).
// attn: flash attention, LDS PV (proven r1), triple-buffered sYt ->
//       ONE barrier/iter; full bpre[4][4] QK prefetch; 2 blocks/CU forced
//       via LDS so each XCD's hot Y-set (4 batches ~2MB) is L2-resident.
// ---------------------------------------------------------------------------

typedef __attribute__((ext_vector_type(8))) short    s8v;  // 8 bf16 = 16B
typedef __attribute__((ext_vector_type(8))) _Float16 h8v;  // 8 f16 = 16B
typedef __attribute__((ext_vector_type(4))) float    f4v;

#define BDIM 256

__device__ __forceinline__ f4v mfma_bf16(s8v a, s8v b, f4v c) {
    return __builtin_amdgcn_mfma_f32_16x16x32_bf16(a, b, c, 0, 0, 0);
}
__device__ __forceinline__ f4v mfma_f16(h8v a, h8v b, f4v c) {
    return __builtin_amdgcn_mfma_f32_16x16x32_f16(a, b, c, 0, 0, 0);
}
// truncation split: v = bf16(hi) + bf16(lo) + O(2^-17 v). 3 VALU ops, no RNE.
__device__ __forceinline__ void tsplit(float v, short& hi, short& lo) {
    unsigned b = __builtin_bit_cast(unsigned, v);
    unsigned hb = b & 0xFFFF0000u;
    float res = v - __builtin_bit_cast(float, hb);
    hi = (short)(hb >> 16);
    lo = (short)(__builtin_bit_cast(unsigned, res) >> 16);
}

typedef const __attribute__((address_space(1))) unsigned int gu32;
typedef __attribute__((address_space(3))) unsigned int lu32;
// async 16B/lane global->LDS; LDS dest = wave-uniform base + lane*16 (m97/m104)
__device__ __forceinline__ void gld_lds16(const void* g, void* l) {
    __builtin_amdgcn_global_load_lds((gu32*)g, (lu32*)l, 16, 0, 0);
}

// ---------------------------------------------------------------------------
// prep: block 0 = mask normalize -> uint8 (proven r3-r7);
//       block 1 = W trunc-split into swizzle-baked bf16 hi/lo planes;
//       blocks 2..1025 = Y -> f16 transposed, XOR-chunk-swizzled, LINEARIZED
//       per (batch, j-tile): the exact byte image attn stages into sYt.
// ---------------------------------------------------------------------------
__global__ __launch_bounds__(1024) void prep_kernel(
    const unsigned int* __restrict__ mraw, unsigned char* __restrict__ nm,
    const float* __restrict__ W, short* __restrict__ Whsw, short* __restrict__ Wlsw,
    const float* __restrict__ Y, _Float16* __restrict__ YTsw)
{
    if (blockIdx.x >= 2) {
        // one block per (batch, j-tile): 64 j-rows x 128 h  ->  16KB f16 tile
        const int tb = blockIdx.x - 2;          // 0..1023
        const int b = tb >> 4, jt = tb & 15;
        __shared__ _Float16 sT[128][64];        // [h][chunk-swizzled j]
        const int tid = threadIdx.x;            // 1024 threads = 128 h x 8 chunks
        const int h = tid & 127, c0 = tid >> 7;
        const float* yb = Y + (size_t)(b * 1024 + jt * 64 + c0 * 8) * 128 + h;
        h8v hv;
        for (int k = 0; k < 8; ++k) hv[k] = (_Float16)yb[k * 128];
        *(h8v*)&sT[h][(c0 ^ (h & 7)) << 3] = hv;   // same swizzle attn's PV reads
        __syncthreads();
        // linear dump: global byte order == swizzled LDS tile order
        *(h8v*)(YTsw + (size_t)tb * 8192 + tid * 8) =
            *(const h8v*)(&sT[0][0] + tid * 8);
        return;
    }
    if (blockIdx.x == 1) {
        for (int idx = threadIdx.x; idx < 16384; idx += 1024) {
            int r = idx >> 7, c = idx & 127;
            short hi, lo; tsplit(W[idx], hi, lo);
            int cs = (((c >> 3) ^ (r & 15)) << 3) | (c & 7);
            Whsw[r * 128 + cs] = hi;
            Wlsw[r * 128 + cs] = lo;
        }
        return;
    }
    __shared__ unsigned int sOrAll, sOrOdd;
    if (threadIdx.x == 0) { sOrAll = 0u; sOrOdd = 0u; }
    __syncthreads();
    unsigned int oa = 0u, oo = 0u;
    for (int i = threadIdx.x; i < 16384; i += 1024) {
        unsigned int v = mraw[i];
        oa |= v;
        if (i & 1) oo |= v;
    }
    atomicOr(&sOrAll, oa);
    atomicOr(&sOrOdd, oo);
    __syncthreads();
    const unsigned int orv = sOrAll, oro = sOrOdd;
    int mode;  // 0 = 4B stride, 1 = uint8, 2 = 2B stride, 3 = int64
    if (orv <= 1u)                       mode = (orv == 1u && oro == 0u) ? 3 : 0;
    else if ((orv & 0xFEFEFEFEu) == 0u)  mode = 1;
    else if ((orv & 0x0000FFFFu) == 0u)  mode = 0;
    else                                 mode = 2;
    const unsigned char*  b8  = (const unsigned char*)mraw;
    const unsigned short* b16 = (const unsigned short*)mraw;
    for (int j = threadIdx.x; j < 65536; j += 1024) {
        unsigned int v;
        if (mode == 0)      v = mraw[j];
        else if (mode == 1) v = b8[j];
        else if (mode == 2) v = b16[j];
        else                v = mraw[2 * j] | mraw[2 * j + 1];
        nm[j] = v ? 1 : 0;
    }
}

// ---------------------------------------------------------------------------
// Projection (all 64 batches): block = 128 rows x 64-h half, 2048 blocks.
// Split-bf16 3-MFMA GEMM, fp32 + bias + relu, stored as ONE f16 plane.
// Per-set compute: raw x loads hoisted (hidden under the barrier), tsplit +
// MFMA + store per set -> peak VGPR ~110 < 128 cap (no spill).
// ---------------------------------------------------------------------------
__global__ __launch_bounds__(BDIM, 4) void proj_kernel(
    const float* __restrict__ X, const float* __restrict__ Y,
    const short* __restrict__ Whsw, const short* __restrict__ Wlsw,
    const float* __restrict__ bias,
    _Float16* __restrict__ XPf, _Float16* __restrict__ YPf)
{
    __shared__ short sW[2][64][128];   // [plane][row in h-half][k swizzled]

    const int gid = blockIdx.x;
    const float* src; _Float16* dst; int local;
    if (gid < 1024) { src = X; dst = XPf; local = gid; }
    else            { src = Y; dst = YPf; local = gid - 1024; }
    const int row0 = (local >> 1) * 128, h0 = (local & 1) * 64;
    const int t = threadIdx.x, w = t >> 6, lane = t & 63, c = lane & 15, q = lane >> 4;

    {
        const short* g0 = Whsw + h0 * 128;
        const short* g1 = Wlsw + h0 * 128;
        short* l0 = &sW[0][0][0];
        short* l1 = &sW[1][0][0];
        for (int i = 0; i < 4; ++i) {
            int off = (t + i * BDIM) * 8;    // 0..8184
            *(s8v*)(l0 + off) = *(const s8v*)(g0 + off);
            *(s8v*)(l1 + off) = *(const s8v*)(g1 + off);
        }
    }

    // raw x loads for both sets, issued before the barrier (latency hidden)
    f4v rawA[2][4], rawB[2][4];
#pragma unroll
    for (int set = 0; set < 2; ++set) {
        const float* xr = src + (size_t)(row0 + w * 32 + set * 16 + c) * 128;
#pragma unroll
        for (int ks = 0; ks < 4; ++ks) {
            rawA[set][ks] = *(const f4v*)&xr[ks * 32 + q * 8];
            rawB[set][ks] = *(const f4v*)&xr[ks * 32 + q * 8 + 4];
        }
    }
    __syncthreads();

    f4v zero = {0.f, 0.f, 0.f, 0.f};
#pragma unroll
    for (int set = 0; set < 2; ++set) {
        s8v ah[4], al[4];
#pragma unroll
        for (int ks = 0; ks < 4; ++ks) {
            for (int k = 0; k < 4; ++k) {
                short hh, ll;
                tsplit(rawA[set][ks][k], hh, ll); ah[ks][k] = hh;     al[ks][k] = ll;
                tsplit(rawB[set][ks][k], hh, ll); ah[ks][4 + k] = hh; al[ks][4 + k] = ll;
            }
        }
        f4v acc[4];
        for (int n = 0; n < 4; ++n) acc[n] = zero;
#pragma unroll
        for (int ks = 0; ks < 4; ++ks) {
            s8v bh[4], bl[4];
            for (int nt = 0; nt < 4; ++nt) {
                int cs = (((ks * 4 + q) ^ c) << 3);       // baked swizzle
                bh[nt] = *(const s8v*)&sW[0][nt * 16 + c][cs];
                bl[nt] = *(const s8v*)&sW[1][nt * 16 + c][cs];
            }
            for (int nt = 0; nt < 4; ++nt) {
                acc[nt] = mfma_bf16(ah[ks], bh[nt], acc[nt]);
                acc[nt] = mfma_bf16(al[ks], bh[nt], acc[nt]);
                acc[nt] = mfma_bf16(ah[ks], bl[nt], acc[nt]);
            }
        }
        for (int nt = 0; nt < 4; ++nt) {
            float bv = bias[h0 + nt * 16 + c];
            for (int r = 0; r < 4; ++r) {
                float v = fmaxf(acc[nt][r] + bv, 0.0f);
                size_t o = (size_t)(row0 + w * 32 + set * 16 + q * 4 + r) * 128
                           + h0 + nt * 16 + c;
                dst[o] = (_Float16)v;
            }
        }
    }
}

// ---------------------------------------------------------------------------
// Flash attention: 1024 blocks = 8 xcd x 16 itile x 8. LDS sized to force
// 2 blocks/CU -> each XCD's concurrent batch set is 4 (~2MB Y-data, L2-
// resident). Triple-buffered sYt (staged via global_load_lds from the
// pre-swizzled YTsw) -> single __syncthreads per j-tile; its vmcnt(0) drain
// only meets L2-hit loads issued >=600cy earlier. QK B-frags fully
// register-prefetched one j-tile ahead (bpre[4][4]) -> no fresh loads in
// the QK dependency chain. PV reads sYt from LDS (conflict-free swizzle).
// ---------------------------------------------------------------------------
__global__ __launch_bounds__(BDIM, 2) void attn_kernel(
    const _Float16* __restrict__ YTsw, const unsigned char* __restrict__ nmask,
    const _Float16* __restrict__ XPf, const _Float16* __restrict__ YPf,
    float* __restrict__ out)
{
    __shared__ _Float16 sYt[3][128][64];  // y^T tiles, chunk c0 at c0^(h&7); 48KB
    __shared__ _Float16 sP[64][72];       // C/D -> A round-trip (wave-private rows)

    const int id = blockIdx.x;
    const int xcd = id & 7, rest = id >> 3;
    const int ibase = (rest & 15) * 64;
    const int b = xcd + 8 * (rest >> 4);        // batch 0..63
    const int t = threadIdx.x, wave = t >> 6, lane = t & 63;
    const int c = lane & 15, q = lane >> 4;
    const int mrow = b * 1024;

    h8v afrag[4];
    {
        const _Float16* xr = XPf + (size_t)(mrow + ibase + wave * 16 + c) * 128;
        for (int ks = 0; ks < 4; ++ks)
            afrag[ks] = *(const h8v*)&xr[ks * 32 + q * 8];
    }

    // stage j-tile 0 into buffer 0 (drains at the jt=0 barrier)
    {
        const char* gw = (const char*)(YTsw + (size_t)(b * 16) * 8192)
                         + wave * 1024 + lane * 16;
        char* lb = (char*)&sYt[0][0][0] + wave * 1024;
        gld_lds16(gw,         lb);
        gld_lds16(gw + 4096,  lb + 4096);
        gld_lds16(gw + 8192,  lb + 8192);
        gld_lds16(gw + 12288, lb + 12288);
    }

    // full QK B prefetch for the CURRENT j-tile: all 4 k-blocks + mask
    h8v bpre[4][4];
    int mk[4];
    for (int nt = 0; nt < 4; ++nt) {
        const _Float16* pb = YPf + (size_t)(mrow + nt * 16 + c) * 128 + q * 8;
        bpre[nt][0] = *(const h8v*)pb;
        bpre[nt][1] = *(const h8v*)(pb + 32);
        bpre[nt][2] = *(const h8v*)(pb + 64);
        bpre[nt][3] = *(const h8v*)(pb + 96);
        mk[nt] = nmask[mrow + nt * 16 + c];
    }

    f4v zero = {0.f, 0.f, 0.f, 0.f};
    float m_i[4], l_i[4];
    f4v o[8];
    for (int r = 0; r < 4; ++r) { m_i[r] = -INFINITY; l_i[r] = 0.f; }
    for (int h = 0; h < 8; ++h) o[h] = zero;

    int cur = 0;
    for (int jt = 0; jt < 16; ++jt) {
        const int jbase = jt * 64;
        int nx = cur + 1; if (nx == 3) nx = 0;

        // stage jt+1 into buffer nx. Safe vs PV(jt-2)'s reads of this buffer:
        // they completed before barrier(jt-1), which precedes this issue.
        if (jt < 15) {
            const char* gw = (const char*)(YTsw + (size_t)(b * 16 + jt + 1) * 8192)
                             + wave * 1024 + lane * 16;
            char* lb = (char*)&sYt[0][0][0] + nx * 16384 + wave * 1024;
            gld_lds16(gw,         lb);
            gld_lds16(gw + 4096,  lb + 4096);
            gld_lds16(gw + 8192,  lb + 8192);
            gld_lds16(gw + 12288, lb + 12288);
        }

        // QK: entirely from prefetched registers -- no loads in the chain
        f4v s[4];
        __builtin_amdgcn_s_setprio(1);
        for (int nt = 0; nt < 4; ++nt) {
            f4v acc = zero;
            acc = mfma_f16(afrag[0], bpre[nt][0], acc);
            acc = mfma_f16(afrag[1], bpre[nt][1], acc);
            acc = mfma_f16(afrag[2], bpre[nt][2], acc);
            acc = mfma_f16(afrag[3], bpre[nt][3], acc);
            if (mk[nt]) { acc[0] = -1e30f; acc[1] = -1e30f; acc[2] = -1e30f; acc[3] = -1e30f; }
            s[nt] = acc;
        }
        __builtin_amdgcn_s_setprio(0);

        // refill bpre for jt+1: drains under softmax (+barrier), used next iter
        if (jt < 15) {
            const int jn = jbase + 64;
            for (int nt = 0; nt < 4; ++nt) {
                const _Float16* pb = YPf + (size_t)(mrow + jn + nt * 16 + c) * 128 + q * 8;
                bpre[nt][0] = *(const h8v*)pb;
                bpre[nt][1] = *(const h8v*)(pb + 32);
                bpre[nt][2] = *(const h8v*)(pb + 64);
                bpre[nt][3] = *(const h8v*)(pb + 96);
            }
        }

        // fp32 online softmax (row r spread across lane&15 of each quad)
        float alpha[4];
        for (int r = 0; r < 4; ++r) {
            float mx = fmaxf(fmaxf(s[0][r], s[1][r]), fmaxf(s[2][r], s[3][r]));
            for (int off = 1; off < 16; off <<= 1)
                mx = fmaxf(mx, __shfl_xor(mx, off, 64));
            float mnew = fmaxf(m_i[r], mx);
            alpha[r] = __expf(m_i[r] - mnew);   // expf(-inf)=0 on first tile
            m_i[r] = mnew;
        }

        // P in f16; masked -> exactly 0; l from the f16-rounded P (cancels)
        float rs[4] = {0.f, 0.f, 0.f, 0.f};
        for (int nt = 0; nt < 4; ++nt) {
            for (int r = 0; r < 4; ++r) {
                float p = mk[nt] ? 0.f : __expf(s[nt][r] - m_i[r]);
                _Float16 ph = (_Float16)p;
                rs[r] += (float)ph;
                sP[wave * 16 + q * 4 + r][nt * 16 + c] = ph;
            }
        }
        for (int r = 0; r < 4; ++r) {
            float sum = rs[r];
            for (int off = 1; off < 16; off <<= 1)
                sum += __shfl_xor(sum, off, 64);
            l_i[r] = l_i[r] * alpha[r] + sum;
        }

        for (int h = 0; h < 8; ++h)
            for (int r = 0; r < 4; ++r)
                o[h][r] *= alpha[r];

        __syncthreads();   // sYt[cur] staged (vmcnt drain: all L2-hit, issued early)

        // mask refill for jt+1: drains by next iter's QK use (vmcnt-tracked)
        if (jt < 15) {
            const int jn = jbase + 64;
            for (int nt = 0; nt < 4; ++nt)
                mk[nt] = nmask[mrow + jn + nt * 16 + c];
        }

        // PV: A from wave-private sP (in-order DS), B from sYt[cur] (swizzled)
        __builtin_amdgcn_s_setprio(1);
        for (int k2 = 0; k2 < 2; ++k2) {
            h8v a = *(const h8v*)&sP[wave * 16 + c][k2 * 32 + q * 8];
            for (int hb = 0; hb < 8; ++hb) {
                h8v bb = *(const h8v*)&sYt[cur][hb * 16 + c][(((k2 << 2) + q) ^ (c & 7)) << 3];
                o[hb] = mfma_f16(a, bb, o[hb]);
            }
        }
        __builtin_amdgcn_s_setprio(0);

        cur = nx;
    }

    for (int h = 0; h < 8; ++h) {
        for (int r = 0; r < 4; ++r) {
            float v = o[h][r] / l_i[r];
            out[(size_t)(mrow + ibase + wave * 16 + q * 4 + r) * 128 + h * 16 + c] = v;
        }
    }
}

// ---------------------------------------------------------------------------
extern "C" void kernel_launch(void* const* d_in, const int* in_sizes, int n_in,
                              void* d_out, int out_size, void* d_ws, size_t ws_size,
                              hipStream_t stream) {
    const float* x    = (const float*)d_in[0];  // [64,1024,128] fp32
    const float* y    = (const float*)d_in[1];
    const unsigned int* mraw = (const unsigned int*)d_in[2];
    const float* W    = (const float*)d_in[3];  // [128,128] fp32
    const float* bias = (const float*)d_in[4];  // [128] fp32
    float* out = (float*)d_out;                 // [64,1024,128] fp32

    // ws: nmask 64KB | Whsw 32KB | Wlsw 32KB | XPf 16MB | YPf 16MB | YTsw 16MB
    unsigned char* nmask = (unsigned char*)d_ws;
    short* Whsw = (short*)((char*)d_ws + 65536);
    short* Wlsw = Whsw + 16384;
    _Float16* XPf = (_Float16*)(Wlsw + 16384);
    _Float16* YPf = XPf + (size_t)64 * 1024 * 128;
    _Float16* YTsw = YPf + (size_t)64 * 1024 * 128;

    prep_kernel<<<1026, 1024, 0, stream>>>(mraw, nmask, W, Whsw, Wlsw, y, YTsw);
    proj_kernel<<<2048, BDIM, 0, stream>>>(x, y, Whsw, Wlsw, bias, XPf, YPf);
    attn_kernel<<<1024, BDIM, 0, stream>>>(YTsw, nmask, XPf, YPf, out);
}